// Round 11
// baseline (219.808 us; speedup 1.0000x reference)
//
#include <hip/hip_runtime.h>
#include <cstdint>

#define N 2048
#define NH 8
#define DI 32
#define DOUT 32
#define BATCH 4
#define LOG2E 1.44269504088896340736f

typedef float f32x4 __attribute__((ext_vector_type(4)));
typedef __bf16 bf16x8 __attribute__((ext_vector_type(8)));

__device__ __forceinline__ unsigned short f2bf(float f) {
    unsigned u = __float_as_uint(f);
    u = u + 0x7fffu + ((u >> 16) & 1u);
    return (unsigned short)(u >> 16);
}

// ---------------- K1: fused prep (blocks 0..255) + pack (blocks 256..8447) ----------------
__global__ __launch_bounds__(256) void k_prep_pack(
    const float* __restrict__ x, const float* __restrict__ att_w,
    const int* __restrict__ adj, float* __restrict__ xi, float* __restrict__ xj,
    unsigned short* __restrict__ xhB, unsigned char* __restrict__ adjb) {
    if (blockIdx.x >= 256) {
        int t = (blockIdx.x - 256) * 256 + threadIdx.x;
        const int4* p = (const int4*)adj + (size_t)t * 2;
        int4 a = p[0], b = p[1];
        unsigned byte = (a.x != 0) | ((a.y != 0) << 1) | ((a.z != 0) << 2) | ((a.w != 0) << 3)
                      | ((b.x != 0) << 4) | ((b.y != 0) << 5) | ((b.z != 0) << 6) | ((b.w != 0) << 7);
        adjb[t] = (unsigned char)byte;
        return;
    }
    int g = blockIdx.x >> 3, chunk = blockIdx.x & 7;
    int b = g >> 3, h = g & 7;
    __shared__ float aw[2 * DI];
    if (threadIdx.x < 2 * DI) aw[threadIdx.x] = att_w[threadIdx.x];
    __syncthreads();

    int i = chunk * 256 + threadIdx.x;
    const float* xr = x + ((size_t)b * N + i) * (NH * DI) + h * DI;
    float si = 0.f, sj = 0.f;
#pragma unroll
    for (int d = 0; d < DI; ++d) {
        float v = xr[d];
        si += v * aw[d];
        sj += v * aw[DI + d];
    }
    xi[g * N + i] = si;
    xj[g * N + i] = sj;

    // B-fragment layout for mfma_f32_16x16x32_bf16 (verified round 1):
    // tiles indexed [g][jt(64)][dh(2)][lane(64)][r(8)]
    for (int t = 0; t < 4; ++t) {
        int item = t * 256 + threadIdx.x;
        int lane = item & 63;
        int dh = (item >> 6) & 1;
        int jt = chunk * 8 + (item >> 7);
        int d = dh * 16 + (lane & 15);
        int j0 = jt * 32 + (lane >> 4) * 8;
        union { unsigned short u[8]; uint4 v; } f;
#pragma unroll
        for (int r = 0; r < 8; ++r) {
            float v = x[((size_t)b * N + j0 + r) * (NH * DI) + h * DI + d];
            f.u[r] = f2bf(v);
        }
        *(uint4*)(xhB + ((((size_t)g * 64 + jt) * 2 + dh) * 64 + lane) * 8) = f.v;
    }
}

// ---------------- K1b: transpose packed adj -> adjT[ab][jt][row] ----------------
// Reads are L2-resident gathers (adjp = 2 MB just written); writes coalesced.
__global__ __launch_bounds__(256) void k_adjT(const unsigned* __restrict__ adjp,
                                              unsigned* __restrict__ adjT) {
    int ab = blockIdx.x >> 6, jt = blockIdx.x & 63;
    const unsigned* src = adjp + ((size_t)ab * N) * 64 + jt;
    unsigned* dst = adjT + ((size_t)(ab * 64 + jt)) * N;
#pragma unroll
    for (int k = 0; k < 8; ++k) {
        int row = k * 256 + threadIdx.x;
        dst[row] = src[(size_t)row * 64];
    }
}

// ---------------- K2: fused role-split main kernel ----------------
// bid -> xcd = bid&7, slot = bid>>3 (<160), gsub = slot/40, rem = slot%40,
// g = gsub*8 + xcd. rem%5==4 -> sum role (sb = rem/5, 256 rows, 4x xhB reuse);
// else store role (it = (rem/5)*4 + rem%5). XCD-local; fine role interleave.
__global__ __launch_bounds__(256, 4) void k_fused(
    const unsigned* __restrict__ adjp, const unsigned* __restrict__ adjT,
    const float* __restrict__ xi_g, const float* __restrict__ xj_g,
    const unsigned short* __restrict__ xhB, const float* __restrict__ fc_w,
    const float* __restrict__ fc_b, float* __restrict__ out0, float* __restrict__ att) {
    int bid = blockIdx.x;
    int xcd = bid & 7, slot = bid >> 3;
    int gsub = slot / 40, rem = slot % 40;
    int g = gsub * 8 + xcd;
    int role_sum = ((rem % 5) == 4);
    int it = (rem / 5) * 4 + (rem % 5);   // store role only
    int sb = rem / 5;                     // sum role only
    int b = g >> 3, h = g & 7, ab = g & 3;
    int tid = threadIdx.x;
    int w = tid >> 6, l = tid & 63;
    int qg = l >> 4, lr = l & 15;

    // LDS (floats): B1[2048] | B2[2048] | union{ADJ 64x65 u32 (store) / AGG 64x33 (sum)}
    //               | FCW 32x33 | FCB 32 | SS 256 | RED 4  => 9604 f = 38.4 KB
    __shared__ alignas(16) float SM[9604];
    float* B1s = SM;
    float* B2s = SM + 2048;
    unsigned* ADJ = (unsigned*)(SM + 4096);
    float* AGG = SM + 4096;
    float* FCW = SM + 8256;
    float* FCB = SM + 9312;
    float* SS  = SM + 9344;
    float* RED = SM + 9600;

    // ---- build B1/B2 tables + per-thread max of xj ----
    float mymax;
    {
        int j8 = tid * 8;
        const float* xjr = xj_g + (size_t)g * N + j8;
        f32x4 xa = *(const f32x4*)xjr;
        f32x4 xc = *(const f32x4*)(xjr + 4);
        f32x4 p1a, p1b, p2a, p2b;
        mymax = -3.4e38f;
#pragma unroll
        for (int k = 0; k < 4; ++k) {
            float v = xa[k];
            p1a[k] = __builtin_amdgcn_exp2f(v * LOG2E);
            p2a[k] = __builtin_amdgcn_exp2f(0.01f * v * LOG2E);
            mymax = fmaxf(mymax, v);
        }
#pragma unroll
        for (int k = 0; k < 4; ++k) {
            float v = xc[k];
            p1b[k] = __builtin_amdgcn_exp2f(v * LOG2E);
            p2b[k] = __builtin_amdgcn_exp2f(0.01f * v * LOG2E);
            mymax = fmaxf(mymax, v);
        }
        *(f32x4*)&B1s[j8] = p1a; *(f32x4*)&B1s[j8 + 4] = p1b;
        *(f32x4*)&B2s[j8] = p2a; *(f32x4*)&B2s[j8 + 4] = p2b;
    }
    if (!role_sum) {
        // store role: stage its 64 packed adj rows
        int row = tid >> 2, seg = tid & 3;
        const uint4* src = (const uint4*)(adjp + (((size_t)ab * N) + it * 64 + row) * 64 + seg * 16);
#pragma unroll
        for (int q = 0; q < 4; ++q) {
            uint4 v = src[q];
            unsigned* dst = &ADJ[row * 65 + seg * 16 + q * 4];
            dst[0] = v.x; dst[1] = v.y; dst[2] = v.z; dst[3] = v.w;
        }
    } else {
        if (tid < 32) FCB[tid] = fc_b[tid];
        float4 v = ((const float4*)fc_w)[tid];
        int row = tid >> 3, c0 = (tid & 7) * 4;
        FCW[row * 33 + c0 + 0] = v.x; FCW[row * 33 + c0 + 1] = v.y;
        FCW[row * 33 + c0 + 2] = v.z; FCW[row * 33 + c0 + 3] = v.w;
    }
#pragma unroll
    for (int off = 32; off >= 1; off >>= 1) mymax = fmaxf(mymax, __shfl_xor(mymax, off, 64));
    if ((tid & 63) == 0) RED[tid >> 6] = mymax;
    __syncthreads();
    float xjm = fmaxf(fmaxf(RED[0], RED[1]), fmaxf(RED[2], RED[3]));

    if (role_sum) {
        // ================= SUM ROLE: 256 rows, 4x xhB register reuse =================
        int R0 = sb * 256;
        float A1[4], A2[4], T[4];
        int rowA[4];
#pragma unroll
        for (int t = 0; t < 4; ++t) {
            rowA[t] = R0 + t * 64 + w * 16 + lr;
            float xiv = xi_g[(size_t)g * N + rowA[t]];
            float vM = xiv + xjm;
            float M = fmaxf(vM, 0.01f * vM);
            A1[t] = __builtin_amdgcn_exp2f((xiv - M) * LOG2E);
            A2[t] = __builtin_amdgcn_exp2f((0.01f * xiv - M) * LOG2E);
            T[t]  = __builtin_amdgcn_exp2f(-xiv * LOG2E);
        }
        const unsigned* adjT_g = adjT + ((size_t)ab * 64) * N;

        f32x4 acc[4][2];
#pragma unroll
        for (int t = 0; t < 4; ++t) {
            acc[t][0] = (f32x4){0.f, 0.f, 0.f, 0.f};
            acc[t][1] = (f32x4){0.f, 0.f, 0.f, 0.f};
        }
        float ssum[4] = {0.f, 0.f, 0.f, 0.f};
        const unsigned short* xb = xhB + (size_t)g * 64 * 2 * 64 * 8;

        const bf16x8* bp0 = (const bf16x8*)(xb + ((size_t)l) * 8);
        bf16x8 b0 = bp0[0];
        bf16x8 b1 = bp0[64];
        unsigned aw[4];
#pragma unroll
        for (int t = 0; t < 4; ++t) aw[t] = adjT_g[rowA[t]];   // jt = 0, coalesced 64B

        for (int jt = 0; jt < 64; ++jt) {
            int jn = (jt + 1) & 63;
            const bf16x8* bpn = (const bf16x8*)(xb + (((size_t)jn * 2) * 64 + l) * 8);
            bf16x8 nb0 = bpn[0];
            bf16x8 nb1 = bpn[64];
            unsigned na[4];
#pragma unroll
            for (int t = 0; t < 4; ++t) na[t] = adjT_g[(size_t)jn * N + rowA[t]];

            int j0 = jt * 32 + qg * 8;
            f32x4 c1a = *(const f32x4*)&B1s[j0];
            f32x4 c1b = *(const f32x4*)&B1s[j0 + 4];
            f32x4 c2a = *(const f32x4*)&B2s[j0];
            f32x4 c2b = *(const f32x4*)&B2s[j0 + 4];
#pragma unroll
            for (int t = 0; t < 4; ++t) {
                unsigned byte = (aw[t] >> (qg * 8)) & 0xffu;
                bf16x8 af;
#pragma unroll
                for (int r = 0; r < 8; ++r) {
                    float b1v = (r < 4) ? c1a[r] : c1b[r - 4];
                    float b2v = (r < 4) ? c2a[r] : c2b[r - 4];
                    bool pos = b1v >= T[t];
                    float v = (pos ? A1[t] : A2[t]) * (pos ? b1v : b2v);
                    float e = ((byte >> r) & 1u) ? v : 0.f;
                    ssum[t] += e;
                    af[r] = (__bf16)e;
                }
                acc[t][0] = __builtin_amdgcn_mfma_f32_16x16x32_bf16(af, b0, acc[t][0], 0, 0, 0);
                acc[t][1] = __builtin_amdgcn_mfma_f32_16x16x32_bf16(af, b1, acc[t][1], 0, 0, 0);
            }
            b0 = nb0; b1 = nb1;
#pragma unroll
            for (int t = 0; t < 4; ++t) aw[t] = na[t];
        }

#pragma unroll
        for (int t = 0; t < 4; ++t) {
            ssum[t] += __shfl_xor(ssum[t], 16, 64);
            ssum[t] += __shfl_xor(ssum[t], 32, 64);
            if (qg == 0) SS[t * 64 + w * 16 + lr] = ssum[t];
        }
        __syncthreads();

#pragma unroll
        for (int t = 0; t < 4; ++t) {
            int r0 = w * 16 + qg * 4;
#pragma unroll
            for (int r = 0; r < 4; ++r) {
                float inv = 1.0f / SS[t * 64 + r0 + r];
                AGG[(r0 + r) * 33 + lr] = acc[t][0][r] * inv;
                AGG[(r0 + r) * 33 + 16 + lr] = acc[t][1][r] * inv;
            }
            __syncthreads();
            {
                int orow = w * 16 + lr;
                int do0 = qg * 8;
                float o[8];
#pragma unroll
                for (int r = 0; r < 8; ++r) o[r] = FCB[do0 + r];
#pragma unroll
                for (int d = 0; d < 32; ++d) {
                    float a = AGG[orow * 33 + d];
#pragma unroll
                    for (int r = 0; r < 8; ++r) o[r] = fmaf(a, FCW[(do0 + r) * 33 + d], o[r]);
                }
                float4 v0 = make_float4(fmaxf(o[0], 0.f), fmaxf(o[1], 0.f), fmaxf(o[2], 0.f), fmaxf(o[3], 0.f));
                float4 v1 = make_float4(fmaxf(o[4], 0.f), fmaxf(o[5], 0.f), fmaxf(o[6], 0.f), fmaxf(o[7], 0.f));
                float* op = out0 + ((size_t)b * N + R0 + t * 64 + orow) * (NH * DOUT) + h * DOUT + do0;
                *(float4*)op = v0;
                *(float4*)(op + 4) = v1;
            }
            __syncthreads();   // AGG safe to overwrite next t
        }
        return;
    }

    // ================= STORE ROLE (rows it*64 .. +63) =================
    int iloc = w * 16 + lr;
    float xiv = xi_g[(size_t)g * N + it * 64 + iloc];
    float vM = xiv + xjm;
    float M = fmaxf(vM, 0.01f * vM);
    float A1 = __builtin_amdgcn_exp2f((xiv - M) * LOG2E);
    float A2 = __builtin_amdgcn_exp2f((0.01f * xiv - M) * LOG2E);
    float T  = __builtin_amdgcn_exp2f(-xiv * LOG2E);

    // Sweep 1: per-row denominators
    {
        float ssum = 0.f;
        for (int jt = 0; jt < 64; ++jt) {
            unsigned byte = (ADJ[iloc * 65 + jt] >> (qg * 8)) & 0xffu;
            int j0 = jt * 32 + qg * 8;
            f32x4 c1a = *(const f32x4*)&B1s[j0];
            f32x4 c1b = *(const f32x4*)&B1s[j0 + 4];
            f32x4 c2a = *(const f32x4*)&B2s[j0];
            f32x4 c2b = *(const f32x4*)&B2s[j0 + 4];
#pragma unroll
            for (int r = 0; r < 8; ++r) {
                float b1v = (r < 4) ? c1a[r] : c1b[r - 4];
                float b2v = (r < 4) ? c2a[r] : c2b[r - 4];
                bool pos = b1v >= T;
                float v = (pos ? A1 : A2) * (pos ? b1v : b2v);
                ssum += ((byte >> r) & 1u) ? v : 0.f;
            }
        }
        ssum += __shfl_xor(ssum, 16, 64);
        ssum += __shfl_xor(ssum, 32, 64);
        if (qg == 0) SS[iloc] = ssum;
    }
    __syncthreads();

    // Sweep 2: dense stores — wave w owns rows 16w..16w+15; contiguous 1 KB per instr.
    for (int rr = 0; rr < 16; ++rr) {
        int row = w * 16 + rr;
        float xiv2 = xi_g[(size_t)g * N + it * 64 + row];   // broadcast
        float vM2 = xiv2 + xjm;
        float M2 = fmaxf(vM2, 0.01f * vM2);
        float invA = 1.0f / SS[row];
        float A1p = __builtin_amdgcn_exp2f((xiv2 - M2) * LOG2E) * invA;
        float A2p = __builtin_amdgcn_exp2f((0.01f * xiv2 - M2) * LOG2E) * invA;
        float T2  = __builtin_amdgcn_exp2f(-xiv2 * LOG2E);
        float* arow = att + ((size_t)g * N + it * 64 + row) * N;
        const unsigned* adjrow = &ADJ[row * 65];
        int sh = 4 * (l & 7);
        int wi = l >> 3;
#pragma unroll
        for (int seg = 0; seg < 4; ++seg) {
            int j0 = seg * 512 + 4 * l;
            unsigned nib0 = (adjrow[seg * 16 + wi] >> sh) & 0xfu;
            unsigned nib1 = (adjrow[seg * 16 + 8 + wi] >> sh) & 0xfu;
            f32x4 b1lo = *(const f32x4*)&B1s[j0];
            f32x4 b2lo = *(const f32x4*)&B2s[j0];
            f32x4 b1hi = *(const f32x4*)&B1s[j0 + 256];
            f32x4 b2hi = *(const f32x4*)&B2s[j0 + 256];
            f32x4 o0, o1;
#pragma unroll
            for (int k = 0; k < 4; ++k) {
                bool p0 = b1lo[k] >= T2;
                float v0 = (p0 ? A1p : A2p) * (p0 ? b1lo[k] : b2lo[k]);
                o0[k] = ((nib0 >> k) & 1u) ? v0 : 0.f;
                bool p1 = b1hi[k] >= T2;
                float v1 = (p1 ? A1p : A2p) * (p1 ? b1hi[k] : b2hi[k]);
                o1[k] = ((nib1 >> k) & 1u) ? v1 : 0.f;
            }
            *(f32x4*)&arow[j0] = o0;
            *(f32x4*)&arow[j0 + 256] = o1;
        }
    }
}

extern "C" void kernel_launch(void* const* d_in, const int* in_sizes, int n_in,
                              void* d_out, int out_size, void* d_ws, size_t ws_size,
                              hipStream_t stream) {
    const float* x = (const float*)d_in[0];
    const int* adj = (const int*)d_in[1];
    const float* att_w = (const float*)d_in[2];
    const float* fc_w = (const float*)d_in[3];
    const float* fc_b = (const float*)d_in[4];

    // Workspace layout (non-overlapping):
    //   adjb/adjp [0,        2097152)   2 MB
    //   adjT      [2097152,  4194304)   2 MB
    //   xi        [4194304,  4456448)   256 KB
    //   xj        [4456448,  4718592)   256 KB
    //   xhB       [4718592,  8912896)   4 MB
    unsigned char* ws = (unsigned char*)d_ws;
    unsigned char* adjb = ws;
    unsigned* adjp = (unsigned*)ws;
    unsigned* adjT = (unsigned*)(ws + 2097152);
    float* xi = (float*)(ws + 4194304);
    float* xj = (float*)(ws + 4456448);
    unsigned short* xhB = (unsigned short*)(ws + 4718592);

    float* out0 = (float*)d_out;
    float* att = out0 + (size_t)BATCH * N * NH * DOUT;

    k_prep_pack<<<256 + (BATCH * N * N) / 8 / 256, 256, 0, stream>>>(x, att_w, adj, xi, xj, xhB, adjb);
    k_adjT<<<256, 256, 0, stream>>>(adjp, adjT);
    k_fused<<<1280, 256, 0, stream>>>(adjp, adjT, xi, xj, xhB, fc_w, fc_b, out0, att);
}

// Round 12
// 133.556 us; speedup vs baseline: 1.6458x; 1.6458x over previous
//
#include <hip/hip_runtime.h>
#include <cstdint>

#define N 2048
#define NH 8
#define DI 32
#define DOUT 32
#define BATCH 4
#define LOG2E 1.44269504088896340736f

typedef float f32x4 __attribute__((ext_vector_type(4)));
typedef __bf16 bf16x8 __attribute__((ext_vector_type(8)));

__device__ __forceinline__ unsigned short f2bf(float f) {
    unsigned u = __float_as_uint(f);
    u = u + 0x7fffu + ((u >> 16) & 1u);
    return (unsigned short)(u >> 16);
}

// ---------------- K1: fused prep (blocks 0..255) + pack (blocks 256..8447) ----------------
__global__ __launch_bounds__(256) void k_prep_pack(
    const float* __restrict__ x, const float* __restrict__ att_w,
    const int* __restrict__ adj, float* __restrict__ xi, float* __restrict__ xj,
    unsigned short* __restrict__ xhB, unsigned char* __restrict__ adjb) {
    if (blockIdx.x >= 256) {
        int t = (blockIdx.x - 256) * 256 + threadIdx.x;
        const int4* p = (const int4*)adj + (size_t)t * 2;
        int4 a = p[0], b = p[1];
        unsigned byte = (a.x != 0) | ((a.y != 0) << 1) | ((a.z != 0) << 2) | ((a.w != 0) << 3)
                      | ((b.x != 0) << 4) | ((b.y != 0) << 5) | ((b.z != 0) << 6) | ((b.w != 0) << 7);
        adjb[t] = (unsigned char)byte;
        return;
    }
    int g = blockIdx.x >> 3, chunk = blockIdx.x & 7;
    int b = g >> 3, h = g & 7;
    __shared__ float aw[2 * DI];
    if (threadIdx.x < 2 * DI) aw[threadIdx.x] = att_w[threadIdx.x];
    __syncthreads();

    int i = chunk * 256 + threadIdx.x;
    const float* xr = x + ((size_t)b * N + i) * (NH * DI) + h * DI;
    float si = 0.f, sj = 0.f;
#pragma unroll
    for (int d = 0; d < DI; ++d) {
        float v = xr[d];
        si += v * aw[d];
        sj += v * aw[DI + d];
    }
    xi[g * N + i] = si;
    xj[g * N + i] = sj;

    // B-fragment layout for mfma_f32_16x16x32_bf16 (verified round 1):
    // tiles indexed [g][jt(64)][dh(2)][lane(64)][r(8)]
    for (int t = 0; t < 4; ++t) {
        int item = t * 256 + threadIdx.x;
        int lane = item & 63;
        int dh = (item >> 6) & 1;
        int jt = chunk * 8 + (item >> 7);
        int d = dh * 16 + (lane & 15);
        int j0 = jt * 32 + (lane >> 4) * 8;
        union { unsigned short u[8]; uint4 v; } f;
#pragma unroll
        for (int r = 0; r < 8; ++r) {
            float v = x[((size_t)b * N + j0 + r) * (NH * DI) + h * DI + d];
            f.u[r] = f2bf(v);
        }
        *(uint4*)(xhB + ((((size_t)g * 64 + jt) * 2 + dh) * 64 + lane) * 8) = f.v;
    }
}

// ---------------- K2: fused role-split main kernel (R10 body + NT att stores) ----------------
// bid -> xcd = bid&7, slot = bid>>3, g = (slot>>6)*8 + xcd, rem = slot&63,
// role = rem&1 (1=sum, 0=store), it = rem>>1. XCD-local read set ~1.5 MB.
// att stores are NONTEMPORAL (dense 1 KB/wave bursts, no L2 allocate) so the
// 537 MB write stream stops evicting xhB/adjp from per-XCD L2.
__global__ __launch_bounds__(256, 4) void k_fused(
    const unsigned* __restrict__ adjp, const float* __restrict__ xi_g,
    const float* __restrict__ xj_g, const unsigned short* __restrict__ xhB,
    const float* __restrict__ fc_w, const float* __restrict__ fc_b,
    float* __restrict__ out0, float* __restrict__ att) {
    int bid = blockIdx.x;
    int xcd = bid & 7, slot = bid >> 3;
    int g = (slot >> 6) * 8 + xcd;
    int rem = slot & 63;
    int role = rem & 1;
    int it = rem >> 1;
    int b = g >> 3, h = g & 7, ab = g & 3;
    int tid = threadIdx.x;
    int w = tid >> 6, l = tid & 63;
    int qg = l >> 4, lr = l & 15;

    // LDS layout (floats): B1[2048] | B2[2048] | ADJ 64x65 (aliased by AGG 64x33
    // after the sum loop) | FCW 32x33 | FCB 32 | SS 64 | RED 4   => 9412 f = 36.8 KB
    __shared__ alignas(16) float SM[9412];
    float* B1s = SM;
    float* B2s = SM + 2048;
    unsigned* ADJ = (unsigned*)(SM + 4096);
    float* AGG = SM + 4096;
    float* FCW = SM + 8256;
    float* FCB = SM + 9312;
    float* SS  = SM + 9344;
    float* RED = SM + 9408;

    // ---- build B1/B2 tables + per-thread max of xj ----
    float mymax;
    {
        int j8 = tid * 8;
        const float* xjr = xj_g + (size_t)g * N + j8;
        f32x4 xa = *(const f32x4*)xjr;
        f32x4 xc = *(const f32x4*)(xjr + 4);
        f32x4 p1a, p1b, p2a, p2b;
        mymax = -3.4e38f;
#pragma unroll
        for (int k = 0; k < 4; ++k) {
            float v = xa[k];
            p1a[k] = __builtin_amdgcn_exp2f(v * LOG2E);
            p2a[k] = __builtin_amdgcn_exp2f(0.01f * v * LOG2E);
            mymax = fmaxf(mymax, v);
        }
#pragma unroll
        for (int k = 0; k < 4; ++k) {
            float v = xc[k];
            p1b[k] = __builtin_amdgcn_exp2f(v * LOG2E);
            p2b[k] = __builtin_amdgcn_exp2f(0.01f * v * LOG2E);
            mymax = fmaxf(mymax, v);
        }
        *(f32x4*)&B1s[j8] = p1a; *(f32x4*)&B1s[j8 + 4] = p1b;
        *(f32x4*)&B2s[j8] = p2a; *(f32x4*)&B2s[j8 + 4] = p2b;
    }
    // ---- stage packed adj rows (both roles) ----
    {
        int row = tid >> 2, seg = tid & 3;
        const uint4* src = (const uint4*)(adjp + (((size_t)ab * N) + it * 64 + row) * 64 + seg * 16);
#pragma unroll
        for (int q = 0; q < 4; ++q) {
            uint4 v = src[q];
            unsigned* dst = &ADJ[row * 65 + seg * 16 + q * 4];
            dst[0] = v.x; dst[1] = v.y; dst[2] = v.z; dst[3] = v.w;
        }
    }
    if (role == 1) {
        if (tid < 32) FCB[tid] = fc_b[tid];
        float4 v = ((const float4*)fc_w)[tid];
        int row = tid >> 3, c0 = (tid & 7) * 4;
        FCW[row * 33 + c0 + 0] = v.x; FCW[row * 33 + c0 + 1] = v.y;
        FCW[row * 33 + c0 + 2] = v.z; FCW[row * 33 + c0 + 3] = v.w;
    }
#pragma unroll
    for (int off = 32; off >= 1; off >>= 1) mymax = fmaxf(mymax, __shfl_xor(mymax, off, 64));
    if ((tid & 63) == 0) RED[tid >> 6] = mymax;
    __syncthreads();
    float xjm = fmaxf(fmaxf(RED[0], RED[1]), fmaxf(RED[2], RED[3]));

    int iloc = w * 16 + lr;
    int i = it * 64 + iloc;
    float xiv = xi_g[(size_t)g * N + i];
    float vM = xiv + xjm;
    float M = fmaxf(vM, 0.01f * vM);
    float A1 = __builtin_amdgcn_exp2f((xiv - M) * LOG2E);
    float A2 = __builtin_amdgcn_exp2f((0.01f * xiv - M) * LOG2E);
    float T  = __builtin_amdgcn_exp2f(-xiv * LOG2E);

    if (role == 1) {
        // ================= SUM ROLE: MFMA agg + denominator + out0 =================
        f32x4 acc0 = {0.f, 0.f, 0.f, 0.f}, acc1 = {0.f, 0.f, 0.f, 0.f};
        float ssum = 0.f;
        const unsigned short* xb = xhB + (size_t)g * 64 * 2 * 64 * 8;

        const bf16x8* bp0 = (const bf16x8*)(xb + ((size_t)l) * 8);
        bf16x8 b0 = bp0[0];
        bf16x8 b1 = bp0[64];

        for (int jt = 0; jt < 64; ++jt) {
            int jn = (jt + 1) & 63;
            const bf16x8* bpn = (const bf16x8*)(xb + (((size_t)jn * 2) * 64 + l) * 8);
            bf16x8 nb0 = bpn[0];
            bf16x8 nb1 = bpn[64];

            unsigned byte = (ADJ[iloc * 65 + jt] >> (qg * 8)) & 0xffu;
            int j0 = jt * 32 + qg * 8;
            f32x4 c1a = *(const f32x4*)&B1s[j0];
            f32x4 c1b = *(const f32x4*)&B1s[j0 + 4];
            f32x4 c2a = *(const f32x4*)&B2s[j0];
            f32x4 c2b = *(const f32x4*)&B2s[j0 + 4];
            bf16x8 af;
#pragma unroll
            for (int r = 0; r < 8; ++r) {
                float b1v = (r < 4) ? c1a[r] : c1b[r - 4];
                float b2v = (r < 4) ? c2a[r] : c2b[r - 4];
                bool pos = b1v >= T;
                float bs = pos ? b1v : b2v;
                float as = pos ? A1 : A2;
                float v = as * bs;
                float e = ((byte >> r) & 1u) ? v : 0.f;
                ssum += e;
                af[r] = (__bf16)e;
            }
            acc0 = __builtin_amdgcn_mfma_f32_16x16x32_bf16(af, b0, acc0, 0, 0, 0);
            acc1 = __builtin_amdgcn_mfma_f32_16x16x32_bf16(af, b1, acc1, 0, 0, 0);
            b0 = nb0;
            b1 = nb1;
        }

        ssum += __shfl_xor(ssum, 16, 64);
        ssum += __shfl_xor(ssum, 32, 64);
        if (qg == 0) SS[iloc] = ssum;
        __syncthreads();   // SS visible + all waves done reading ADJ (AGG aliases it)

        {
            int r0 = w * 16 + qg * 4;
#pragma unroll
            for (int r = 0; r < 4; ++r) {
                float inv = 1.0f / SS[r0 + r];
                AGG[(r0 + r) * 33 + lr] = acc0[r] * inv;
                AGG[(r0 + r) * 33 + 16 + lr] = acc1[r] * inv;
            }
        }
        __syncthreads();
        {
            int orow = w * 16 + lr;
            int do0 = qg * 8;
            float o[8];
#pragma unroll
            for (int r = 0; r < 8; ++r) o[r] = FCB[do0 + r];
#pragma unroll
            for (int d = 0; d < 32; ++d) {
                float a = AGG[orow * 33 + d];
#pragma unroll
                for (int r = 0; r < 8; ++r) o[r] = fmaf(a, FCW[(do0 + r) * 33 + d], o[r]);
            }
            float4 v0 = make_float4(fmaxf(o[0], 0.f), fmaxf(o[1], 0.f), fmaxf(o[2], 0.f), fmaxf(o[3], 0.f));
            float4 v1 = make_float4(fmaxf(o[4], 0.f), fmaxf(o[5], 0.f), fmaxf(o[6], 0.f), fmaxf(o[7], 0.f));
            float* op = out0 + ((size_t)b * N + it * 64 + orow) * (NH * DOUT) + h * DOUT + do0;
            *(float4*)op = v0;
            *(float4*)(op + 4) = v1;
        }
        return;
    }

    // ================= STORE ROLE =================
    // Sweep 1: per-row denominators
    {
        float ssum = 0.f;
        for (int jt = 0; jt < 64; ++jt) {
            unsigned byte = (ADJ[iloc * 65 + jt] >> (qg * 8)) & 0xffu;
            int j0 = jt * 32 + qg * 8;
            f32x4 c1a = *(const f32x4*)&B1s[j0];
            f32x4 c1b = *(const f32x4*)&B1s[j0 + 4];
            f32x4 c2a = *(const f32x4*)&B2s[j0];
            f32x4 c2b = *(const f32x4*)&B2s[j0 + 4];
#pragma unroll
            for (int r = 0; r < 8; ++r) {
                float b1v = (r < 4) ? c1a[r] : c1b[r - 4];
                float b2v = (r < 4) ? c2a[r] : c2b[r - 4];
                bool pos = b1v >= T;
                float v = (pos ? A1 : A2) * (pos ? b1v : b2v);
                ssum += ((byte >> r) & 1u) ? v : 0.f;
            }
        }
        ssum += __shfl_xor(ssum, 16, 64);
        ssum += __shfl_xor(ssum, 32, 64);
        if (qg == 0) SS[iloc] = ssum;
    }
    __syncthreads();

    // Sweep 2: dense NT stores — wave w owns rows 16w..16w+15; each wave store is
    // one contiguous 1 KB burst (16 B at byte 16*l), so no L2 assembly needed;
    // nt keeps the 537 MB stream from evicting xhB/adjp out of per-XCD L2.
    for (int rr = 0; rr < 16; ++rr) {
        int row = w * 16 + rr;
        float xiv2 = xi_g[(size_t)g * N + it * 64 + row];   // broadcast
        float vM2 = xiv2 + xjm;
        float M2 = fmaxf(vM2, 0.01f * vM2);
        float invA = 1.0f / SS[row];
        float A1p = __builtin_amdgcn_exp2f((xiv2 - M2) * LOG2E) * invA;
        float A2p = __builtin_amdgcn_exp2f((0.01f * xiv2 - M2) * LOG2E) * invA;
        float T2  = __builtin_amdgcn_exp2f(-xiv2 * LOG2E);
        float* arow = att + ((size_t)g * N + it * 64 + row) * N;
        const unsigned* adjrow = &ADJ[row * 65];
        int sh = 4 * (l & 7);
        int wi = l >> 3;
#pragma unroll
        for (int seg = 0; seg < 4; ++seg) {
            int j0 = seg * 512 + 4 * l;
            unsigned nib0 = (adjrow[seg * 16 + wi] >> sh) & 0xfu;
            unsigned nib1 = (adjrow[seg * 16 + 8 + wi] >> sh) & 0xfu;
            f32x4 b1lo = *(const f32x4*)&B1s[j0];
            f32x4 b2lo = *(const f32x4*)&B2s[j0];
            f32x4 b1hi = *(const f32x4*)&B1s[j0 + 256];
            f32x4 b2hi = *(const f32x4*)&B2s[j0 + 256];
            f32x4 o0, o1;
#pragma unroll
            for (int k = 0; k < 4; ++k) {
                bool p0 = b1lo[k] >= T2;
                float v0 = (p0 ? A1p : A2p) * (p0 ? b1lo[k] : b2lo[k]);
                o0[k] = ((nib0 >> k) & 1u) ? v0 : 0.f;
                bool p1 = b1hi[k] >= T2;
                float v1 = (p1 ? A1p : A2p) * (p1 ? b1hi[k] : b2hi[k]);
                o1[k] = ((nib1 >> k) & 1u) ? v1 : 0.f;
            }
            __builtin_nontemporal_store(o0, (f32x4*)&arow[j0]);
            __builtin_nontemporal_store(o1, (f32x4*)&arow[j0 + 256]);
        }
    }
}

extern "C" void kernel_launch(void* const* d_in, const int* in_sizes, int n_in,
                              void* d_out, int out_size, void* d_ws, size_t ws_size,
                              hipStream_t stream) {
    const float* x = (const float*)d_in[0];
    const int* adj = (const int*)d_in[1];
    const float* att_w = (const float*)d_in[2];
    const float* fc_w = (const float*)d_in[3];
    const float* fc_b = (const float*)d_in[4];

    // Workspace layout (non-overlapping):
    //   adjb/adjp [0,        2097152)   2 MB
    //   xi        [2097152,  2359296)   256 KB
    //   xj        [2359296,  2621440)   256 KB
    //   xhB       [2621440,  6815744)   4 MB
    unsigned char* ws = (unsigned char*)d_ws;
    unsigned char* adjb = ws;
    unsigned* adjp = (unsigned*)ws;
    float* xi = (float*)(ws + 2097152);
    float* xj = (float*)(ws + 2359296);
    unsigned short* xhB = (unsigned short*)(ws + 2621440);

    float* out0 = (float*)d_out;
    float* att = out0 + (size_t)BATCH * N * NH * DOUT;

    k_prep_pack<<<256 + (BATCH * N * N) / 8 / 256, 256, 0, stream>>>(x, att_w, adj, xi, xj, xhB, adjb);
    k_fused<<<2048, 256, 0, stream>>>(adjp, xi, xj, xhB, fc_w, fc_b, out0, att);
}